// Round 7
// baseline (189.517 us; speedup 1.0000x reference)
//
#include <hip/hip_runtime.h>

// relu(sum(relu(x))) over N=2^25 fp32.
// Kernel 1: 2048 blocks x 256 threads, block-contiguous 64 KB slabs, 16
//           batched float4 loads/thread. CACHED loads this round (R7 A/B vs
//           R6's nt): R1 counter evidence (FETCH_SIZE = 65.5 MB = half of x)
//           says the harness restore leaves ~half of x L3-resident; under the
//           ~64-outstanding-requests/CU cap (all read streams on this machine
//           cluster at ~3.1 TB/s while fills do 6.9), L3-hit latency (~350 vs
//           ~900 cy) is the only remaining BW lever. nt forfeits it.
// Kernel 2: 1 block reduces 2048 partials, applies outer ReLU.

typedef float f32x4 __attribute__((ext_vector_type(4)));

#define NBLOCKS 2048
#define TPB     256
#define PER     16   // 2048 blocks * 256 thr * 16 = 2^23 float4 = 2^25 floats

__global__ __launch_bounds__(TPB) void kan_partial(const f32x4* __restrict__ x4,
                                                   float* __restrict__ partials) {
    // Block-contiguous slab: block b covers [b*4096, (b+1)*4096) float4s.
    const f32x4* base = x4 + (size_t)blockIdx.x * (TPB * PER) + threadIdx.x;

    // Phase 1: issue all 16 loads, no intervening consumer.
    f32x4 v[PER];
    #pragma unroll
    for (int i = 0; i < PER; ++i)
        v[i] = base[i * TPB];

    // Phase 2: 4 independent accumulator chains, consumed in issue order so
    // the compiler can retire vmcnt slots progressively.
    float s0 = 0.0f, s1 = 0.0f, s2 = 0.0f, s3 = 0.0f;
    #pragma unroll
    for (int i = 0; i < PER; i += 4) {
        s0 += fmaxf(v[i+0].x, 0.0f) + fmaxf(v[i+0].y, 0.0f) + fmaxf(v[i+0].z, 0.0f) + fmaxf(v[i+0].w, 0.0f);
        s1 += fmaxf(v[i+1].x, 0.0f) + fmaxf(v[i+1].y, 0.0f) + fmaxf(v[i+1].z, 0.0f) + fmaxf(v[i+1].w, 0.0f);
        s2 += fmaxf(v[i+2].x, 0.0f) + fmaxf(v[i+2].y, 0.0f) + fmaxf(v[i+2].z, 0.0f) + fmaxf(v[i+2].w, 0.0f);
        s3 += fmaxf(v[i+3].x, 0.0f) + fmaxf(v[i+3].y, 0.0f) + fmaxf(v[i+3].z, 0.0f) + fmaxf(v[i+3].w, 0.0f);
    }
    float s = (s0 + s1) + (s2 + s3);

    // wave-64 reduction
    #pragma unroll
    for (int off = 32; off > 0; off >>= 1)
        s += __shfl_down(s, off, 64);

    __shared__ float wsum[TPB / 64];
    const int lane = threadIdx.x & 63;
    const int wid  = threadIdx.x >> 6;
    if (lane == 0) wsum[wid] = s;
    __syncthreads();

    if (threadIdx.x == 0)
        partials[blockIdx.x] = wsum[0] + wsum[1] + wsum[2] + wsum[3];
}

__global__ __launch_bounds__(TPB) void kan_final(const float* __restrict__ partials,
                                                 float* __restrict__ out) {
    // 2048 partials, 256 threads -> 8 each; batch loads, then add.
    float p[NBLOCKS / TPB];
    #pragma unroll
    for (int i = 0; i < NBLOCKS / TPB; ++i)
        p[i] = partials[threadIdx.x + i * TPB];

    float s = 0.0f;
    #pragma unroll
    for (int i = 0; i < NBLOCKS / TPB; ++i)
        s += p[i];

    #pragma unroll
    for (int off = 32; off > 0; off >>= 1)
        s += __shfl_down(s, off, 64);

    __shared__ float wsum[TPB / 64];
    const int lane = threadIdx.x & 63;
    const int wid  = threadIdx.x >> 6;
    if (lane == 0) wsum[wid] = s;
    __syncthreads();

    if (threadIdx.x == 0) {
        float total = wsum[0] + wsum[1] + wsum[2] + wsum[3];
        out[0] = fmaxf(total, 0.0f);
    }
}

extern "C" void kernel_launch(void* const* d_in, const int* in_sizes, int n_in,
                              void* d_out, int out_size, void* d_ws, size_t ws_size,
                              hipStream_t stream) {
    const f32x4* x4 = (const f32x4*)d_in[0];
    float* out = (float*)d_out;
    float* partials = (float*)d_ws;  // 2048 floats, all written by kan_partial

    kan_partial<<<NBLOCKS, TPB, 0, stream>>>(x4, partials);
    kan_final<<<1, TPB, 0, stream>>>(partials, out);
}

// Round 8
// 174.933 us; speedup vs baseline: 1.0834x; 1.0834x over previous
//
#include <hip/hip_runtime.h>

// relu(sum(relu(x))) over N=2^25 fp32 — FINAL (R6 structure restored).
//
// Kernel 1: 2048 blocks x 256 threads. Each block owns a contiguous 64 KB slab
//           (4096 float4); 16 nontemporal float4 loads/thread batched into a
//           register array (all in flight before first vmcnt wait), then a
//           4-chain relu+sum tree, wave-64 shuffle reduce, LDS across 4 waves,
//           one plain store per block. No atomics.
// Kernel 2: 1 block reduces 2048 partials, applies outer ReLU.
//
// Evidence trail (rounds 1-7):
//  - nt > cached in both layouts (176/181 vs 189/189): x is L3-cold at kernel
//    time (512 MB ws-poison evicts it); nt skips L2/L3 allocation on a
//    read-once stream.
//  - blocked slabs > 8MB-strided streams (176 vs 181): 2048 sequential
//    address streams vs 32K.
//  - load depth 8 vs 16 neutral; same-address atomics cost ~100 us (R1).
//  - Kernel read BW ~2.9 TB/s vs machine's demonstrated read ceiling ~3.15
//    TB/s (copy reads 3.15, restore 3.2, write-only fills 6.9) -> read-return
//    path cap, not fixable from source.

typedef float f32x4 __attribute__((ext_vector_type(4)));

#define NBLOCKS 2048
#define TPB     256
#define PER     16   // 2048 blocks * 256 thr * 16 = 2^23 float4 = 2^25 floats

__global__ __launch_bounds__(TPB) void kan_partial(const f32x4* __restrict__ x4,
                                                   float* __restrict__ partials) {
    // Block-contiguous slab: block b covers [b*4096, (b+1)*4096) float4s.
    const f32x4* base = x4 + (size_t)blockIdx.x * (TPB * PER) + threadIdx.x;

    // Phase 1: issue all 16 loads, no intervening consumer.
    f32x4 v[PER];
    #pragma unroll
    for (int i = 0; i < PER; ++i)
        v[i] = __builtin_nontemporal_load(base + i * TPB);

    // Phase 2: 4 independent accumulator chains, consumed in issue order.
    float s0 = 0.0f, s1 = 0.0f, s2 = 0.0f, s3 = 0.0f;
    #pragma unroll
    for (int i = 0; i < PER; i += 4) {
        s0 += fmaxf(v[i+0].x, 0.0f) + fmaxf(v[i+0].y, 0.0f) + fmaxf(v[i+0].z, 0.0f) + fmaxf(v[i+0].w, 0.0f);
        s1 += fmaxf(v[i+1].x, 0.0f) + fmaxf(v[i+1].y, 0.0f) + fmaxf(v[i+1].z, 0.0f) + fmaxf(v[i+1].w, 0.0f);
        s2 += fmaxf(v[i+2].x, 0.0f) + fmaxf(v[i+2].y, 0.0f) + fmaxf(v[i+2].z, 0.0f) + fmaxf(v[i+2].w, 0.0f);
        s3 += fmaxf(v[i+3].x, 0.0f) + fmaxf(v[i+3].y, 0.0f) + fmaxf(v[i+3].z, 0.0f) + fmaxf(v[i+3].w, 0.0f);
    }
    float s = (s0 + s1) + (s2 + s3);

    // wave-64 reduction
    #pragma unroll
    for (int off = 32; off > 0; off >>= 1)
        s += __shfl_down(s, off, 64);

    __shared__ float wsum[TPB / 64];
    const int lane = threadIdx.x & 63;
    const int wid  = threadIdx.x >> 6;
    if (lane == 0) wsum[wid] = s;
    __syncthreads();

    if (threadIdx.x == 0)
        partials[blockIdx.x] = wsum[0] + wsum[1] + wsum[2] + wsum[3];
}

__global__ __launch_bounds__(TPB) void kan_final(const float* __restrict__ partials,
                                                 float* __restrict__ out) {
    // 2048 partials, 256 threads -> 8 each; batch loads, then add.
    float p[NBLOCKS / TPB];
    #pragma unroll
    for (int i = 0; i < NBLOCKS / TPB; ++i)
        p[i] = partials[threadIdx.x + i * TPB];

    float s = 0.0f;
    #pragma unroll
    for (int i = 0; i < NBLOCKS / TPB; ++i)
        s += p[i];

    #pragma unroll
    for (int off = 32; off > 0; off >>= 1)
        s += __shfl_down(s, off, 64);

    __shared__ float wsum[TPB / 64];
    const int lane = threadIdx.x & 63;
    const int wid  = threadIdx.x >> 6;
    if (lane == 0) wsum[wid] = s;
    __syncthreads();

    if (threadIdx.x == 0) {
        float total = wsum[0] + wsum[1] + wsum[2] + wsum[3];
        out[0] = fmaxf(total, 0.0f);
    }
}

extern "C" void kernel_launch(void* const* d_in, const int* in_sizes, int n_in,
                              void* d_out, int out_size, void* d_ws, size_t ws_size,
                              hipStream_t stream) {
    const f32x4* x4 = (const f32x4*)d_in[0];
    float* out = (float*)d_out;
    float* partials = (float*)d_ws;  // 2048 floats, all written by kan_partial

    kan_partial<<<NBLOCKS, TPB, 0, stream>>>(x4, partials);
    kan_final<<<1, TPB, 0, stream>>>(partials, out);
}